// Round 4
// baseline (523.007 us; speedup 1.0000x reference)
//
#include <hip/hip_runtime.h>
#include <hip/hip_bf16.h>
#include <math.h>

// LinearAttention: b=16, c=512, n=4096, heads=8, dim_head=64, hidden=512.
// R7 == R6 resubmit (R3 bench was an infra failure; source unchanged):
//  0. xT[b] (4096x512 bf16) = transpose+cast x; wkv bf16; WqT bf16
//  1. kv[b] (1024x4096 bf16) = Wkv @ x  [gemm256 deep-pipe MFMA]  (68.7 GF)
//  2. row_stats: per K-row max & 1/sum_exp (read-only)
//  3. ctx[bh] = softmax(K) @ V^T  [MFMA, exp fused in staging, split-K 8]
//  4. W2[b] = w_out (x) ctx   (fp32 gemm64, writes bf16)
//  5. W3[b] = W2 @ Wq  [old 128^2 MFMA, bf16 out]
//  6. out[b] = W3 @ x + b_out  [gemm256 deep-pipe MFMA, fp32 out] (34.4 GF)
//
// gemm256: 256x256 tile, BK=32, 512 thr / 8 waves (2Mx4N),
//   4-deep LDS pipeline (4 slots x 32KB = 128 KiB), counted vmcnt(8)
//   at tile boundaries (never 0 in main loop), raw s_barrier,
//   setprio(1) around 16-MFMA clusters, sched_barrier(0) after
//   phase-end barriers. LDS granule-major layout [kg][row]:
//   conflict-free ds_read_b128 AND linear global_load_lds dest.
//   XCD-chunked bijective grid swizzle.

typedef __attribute__((ext_vector_type(8))) __bf16 bf16x8;
typedef __attribute__((ext_vector_type(4))) float f32x4;

__device__ inline void async_ld16(const void* g, void* s) {
    __builtin_amdgcn_global_load_lds(
        (const __attribute__((address_space(1))) void*)g,
        (__attribute__((address_space(3))) void*)s, 16, 0, 0);
}

template<int N> __device__ __forceinline__ void end_wait() {
    if constexpr (N == 8)      asm volatile("s_waitcnt vmcnt(8)" ::: "memory");
    else if constexpr (N == 4) asm volatile("s_waitcnt vmcnt(4)" ::: "memory");
    else if constexpr (N == 0) asm volatile("s_waitcnt vmcnt(0)" ::: "memory");
    // N < 0: no wait
}

// ---------------------------------------------------------------------------
// gemm256: C[m][n] = sum_k A[m][k] * BT[n][k]
// BM=BN=256, BK=32, 512 threads (8 waves: 2M x 4N), 16x16x32 bf16 MFMA.
// LDS: As/Bs 4 slots x [granule kg 0..3][row 0..255] x 16B  (64KB each).
// Pipeline: prologue stages tiles 0..2; iter t computes tile t (2 phases,
// 16 MFMA each), stages tile t+3 (A in phase0, B in phase1), ends with
// vmcnt(8) + barrier (tiles t+2,t+3 = 8 loads stay in flight).
// ---------------------------------------------------------------------------
template<bool STAGE, int ENDVM>
__device__ __forceinline__ void tile_body(
    __bf16* As, __bf16* Bs, int slot, int kt,
    const __bf16* srcA0, const __bf16* srcA1,
    const __bf16* srcB0, const __bf16* srcB1,
    int dstA0, int dstA1, int dstB0, int dstB1,
    int aBaseOff, int bBaseOff, f32x4 (&acc)[8][4])
{
    const int so = slot * 8192;
    bf16x8 bfr[4], af[4];

    // ---- phase 0: quadrant mf 0..3, full K=32 ----
    #pragma unroll
    for (int nf = 0; nf < 4; nf++)
        bfr[nf] = *(const bf16x8*)&Bs[so + bBaseOff + nf * 128];
    #pragma unroll
    for (int mf = 0; mf < 4; mf++)
        af[mf] = *(const bf16x8*)&As[so + aBaseOff + mf * 128];
    if (STAGE) {
        const int ns = (kt & 3) * 8192;
        async_ld16(srcA0 + (long)kt * 32, &As[ns + dstA0]);
        async_ld16(srcA1 + (long)kt * 32, &As[ns + dstA1]);
    }
    __builtin_amdgcn_s_barrier();
    __builtin_amdgcn_s_setprio(1);
    #pragma unroll
    for (int mf = 0; mf < 4; mf++)
        #pragma unroll
        for (int nf = 0; nf < 4; nf++)
            acc[mf][nf] = __builtin_amdgcn_mfma_f32_16x16x32_bf16(af[mf], bfr[nf], acc[mf][nf], 0, 0, 0);
    __builtin_amdgcn_s_setprio(0);
    __builtin_amdgcn_s_barrier();
    __builtin_amdgcn_sched_barrier(0);

    // ---- phase 1: quadrant mf 4..7, B frags reused from registers ----
    #pragma unroll
    for (int mf = 0; mf < 4; mf++)
        af[mf] = *(const bf16x8*)&As[so + aBaseOff + (4 + mf) * 128];
    if (STAGE) {
        const int ns = (kt & 3) * 8192;
        async_ld16(srcB0 + (long)kt * 32, &Bs[ns + dstB0]);
        async_ld16(srcB1 + (long)kt * 32, &Bs[ns + dstB1]);
    }
    __builtin_amdgcn_s_barrier();
    __builtin_amdgcn_s_setprio(1);
    #pragma unroll
    for (int mf = 0; mf < 4; mf++)
        #pragma unroll
        for (int nf = 0; nf < 4; nf++)
            acc[4 + mf][nf] = __builtin_amdgcn_mfma_f32_16x16x32_bf16(af[mf], bfr[nf], acc[4 + mf][nf], 0, 0, 0);
    __builtin_amdgcn_s_setprio(0);
    end_wait<ENDVM>();
    __builtin_amdgcn_s_barrier();
    __builtin_amdgcn_sched_barrier(0);
}

template<bool OUTBF, bool BIAS>
__global__ __launch_bounds__(512, 2) void gemm256(
    const __bf16* __restrict__ A, const __bf16* __restrict__ BT,
    void* __restrict__ Cv, const float* __restrict__ bias,
    int K, int N, long aBS, long bBS, long cBS)
{
    __shared__ __align__(16) __bf16 As[4 * 8192];   // 64 KiB
    __shared__ __align__(16) __bf16 Bs[4 * 8192];   // 64 KiB

    const int tid  = threadIdx.x;
    const int lane = tid & 63, wv = tid >> 6;
    const int lr = lane & 15, kg = lane >> 4;
    const int wm = wv >> 2, wn = wv & 3;            // 2 M-waves x 4 N-waves

    // --- XCD-chunked bijective grid swizzle ---
    const int gx = gridDim.x, gy = gridDim.y;
    const unsigned nwg = gx * gy * gridDim.z;
    const unsigned orig = (blockIdx.z * gy + blockIdx.y) * gx + blockIdx.x;
    const unsigned q = nwg >> 3;
    const unsigned w = (orig & 7) * q + (orig >> 3);
    const unsigned perz = gx * gy;
    const int z  = w / perz;
    const unsigned rem = w - z * perz;
    const int by = rem / gx, bx = rem - (rem / gx) * gx;
    const int row0 = by * 256, col0 = bx * 256;

    A  += (long)z * aBS;
    BT += (long)z * bBS;

    // --- staging assignment: thread covers (granule g, row r) slots ---
    const int rowS = tid & 255;
    const int gA0 = (tid >> 8);                     // load 0: g = 0 or 1
    const int gA1 = gA0 + 2;                        // load 1: g = 2 or 3
    const __bf16* srcA0 = A + (long)(row0 + rowS) * K + gA0 * 8;
    const __bf16* srcA1 = A + (long)(row0 + rowS) * K + gA1 * 8;
    const __bf16* srcB0 = BT + (long)(col0 + rowS) * K + gA0 * 8;
    const __bf16* srcB1 = BT + (long)(col0 + rowS) * K + gA1 * 8;
    const int dstA0 = gA0 * 2048 + rowS * 8;
    const int dstA1 = gA1 * 2048 + rowS * 8;
    const int dstB0 = dstA0;                        // Bs has identical layout
    const int dstB1 = dstA1;

    // --- fragment read offsets (granule-major: [kg][row] of 16B) ---
    const int aBaseOff = kg * 2048 + (wm * 128 + lr) * 8;
    const int bBaseOff = kg * 2048 + (wn * 64 + lr) * 8;

    f32x4 acc[8][4] = {};

    const int nt = K >> 5;                          // 32-wide K tiles (=16)

    // --- prologue: stage tiles 0,1,2 into slots 0,1,2 ---
    #pragma unroll
    for (int p = 0; p < 3; p++) {
        const int ns = p * 8192;
        async_ld16(srcA0 + p * 32, &As[ns + dstA0]);
        async_ld16(srcA1 + p * 32, &As[ns + dstA1]);
        async_ld16(srcB0 + p * 32, &Bs[ns + dstB0]);
        async_ld16(srcB1 + p * 32, &Bs[ns + dstB1]);
    }
    asm volatile("s_waitcnt vmcnt(8)" ::: "memory"); // tile 0 resident
    __builtin_amdgcn_s_barrier();
    __builtin_amdgcn_sched_barrier(0);

    int t = 0;
    for (; t < nt - 3; ++t)
        tile_body<true, 8>(As, Bs, t & 3, t + 3, srcA0, srcA1, srcB0, srcB1,
                           dstA0, dstA1, dstB0, dstB1, aBaseOff, bBaseOff, acc);
    tile_body<false, 4>(As, Bs, t & 3, 0, srcA0, srcA1, srcB0, srcB1,
                        dstA0, dstA1, dstB0, dstB1, aBaseOff, bBaseOff, acc); ++t;
    tile_body<false, 0>(As, Bs, t & 3, 0, srcA0, srcA1, srcB0, srcB1,
                        dstA0, dstA1, dstB0, dstB1, aBaseOff, bBaseOff, acc); ++t;
    tile_body<false, -1>(As, Bs, t & 3, 0, srcA0, srcA1, srcB0, srcB1,
                         dstA0, dstA1, dstB0, dstB1, aBaseOff, bBaseOff, acc);

    // --- epilogue ---
    const int kg4 = kg * 4;
    #pragma unroll
    for (int mf = 0; mf < 8; mf++) {
        #pragma unroll
        for (int nf = 0; nf < 4; nf++) {
            #pragma unroll
            for (int rr = 0; rr < 4; rr++) {
                int row = row0 + wm * 128 + mf * 16 + kg4 + rr;
                int col = col0 + wn * 64 + nf * 16 + lr;
                float v = acc[mf][nf][rr];
                if (OUTBF) {
                    ((__hip_bfloat16*)Cv)[(long)z * cBS + (long)row * N + col] = __float2bfloat16(v);
                } else {
                    if (BIAS) v += bias[row];
                    ((float*)Cv)[(long)z * cBS + (long)row * N + col] = v;
                }
            }
        }
    }
}

// ---------------------------------------------------------------------------
// Old 128x128 MFMA GEMM (kept for W3: M=N=512, grid too small for 256^2)
// ---------------------------------------------------------------------------
template<bool OUTBF, bool BIAS>
__global__ __launch_bounds__(256) void gemm_mfma(
    const __bf16* __restrict__ A, const __bf16* __restrict__ BT,
    void* __restrict__ Cv, const float* __restrict__ bias,
    int K, int N, long aBS, long bBS, long cBS)
{
    __shared__ __bf16 As[128 * 64];
    __shared__ __bf16 Bs[128 * 64];

    const int t = threadIdx.x;
    const int lane = t & 63, wv = t >> 6;
    const int z = blockIdx.z;

    const int nx = gridDim.x, ny = gridDim.y;
    const int orig = blockIdx.y * nx + blockIdx.x;
    const int cpx = (nx * ny) >> 3;
    const int w = (orig & 7) * cpx + (orig >> 3);
    const int bx = w / ny, by = w % ny;
    const int row0 = by * 128, col0 = bx * 128;

    A  += (long)z * aBS;
    BT += (long)z * bBS;

    const int wm = (wv >> 1) * 64, wn = (wv & 1) * 64;
    const int lr = lane & 15, kg = lane >> 4;

    f32x4 acc[4][4] = {};

    const int srow = t >> 3;
    const int gsrc = (t & 7) ^ ((t >> 3) & 7);
    const int swzR = lr & 7;

    for (int k0 = 0; k0 < K; k0 += 64) {
        #pragma unroll
        for (int rnd = 0; rnd < 4; rnd++) {
            int r = rnd * 32 + srow;
            async_ld16(A  + (long)(row0 + r) * K + k0 + gsrc * 8, &As[rnd * 2048 + t * 8]);
            async_ld16(BT + (long)(col0 + r) * K + k0 + gsrc * 8, &Bs[rnd * 2048 + t * 8]);
        }
        __syncthreads();

        #pragma unroll
        for (int kk = 0; kk < 2; kk++) {
            bf16x8 af[4], bfr[4];
            int ga = ((kk << 2) | kg) ^ swzR;
            #pragma unroll
            for (int i = 0; i < 4; i++) {
                af[i]  = *(const bf16x8*)&As[(wm + i * 16 + lr) * 64 + ga * 8];
                bfr[i] = *(const bf16x8*)&Bs[(wn + i * 16 + lr) * 64 + ga * 8];
            }
            #pragma unroll
            for (int i = 0; i < 4; i++)
                #pragma unroll
                for (int j = 0; j < 4; j++)
                    acc[i][j] = __builtin_amdgcn_mfma_f32_16x16x32_bf16(af[i], bfr[j], acc[i][j], 0, 0, 0);
        }
        __syncthreads();
    }

    #pragma unroll
    for (int i = 0; i < 4; i++) {
        #pragma unroll
        for (int j = 0; j < 4; j++) {
            #pragma unroll
            for (int r = 0; r < 4; r++) {
                int row = row0 + wm + i * 16 + kg * 4 + r;
                int col = col0 + wn + j * 16 + lr;
                float v = acc[i][j][r];
                if (OUTBF) {
                    ((__hip_bfloat16*)Cv)[(long)z * cBS + (long)row * N + col] = __float2bfloat16(v);
                } else {
                    if (BIAS) v += bias[row];
                    ((float*)Cv)[(long)z * cBS + (long)row * N + col] = v;
                }
            }
        }
    }
}

// ---------------------------------------------------------------------------
// Transpose+cast: x (16,512,4096) f32 -> xT (16,4096,512) bf16
// ---------------------------------------------------------------------------
__global__ __launch_bounds__(256) void transpose_cast(
    const float* __restrict__ x, __hip_bfloat16* __restrict__ xT)
{
    __shared__ float tile[32][33];
    int z = blockIdx.z;
    int n0 = blockIdx.x * 32, c0 = blockIdx.y * 32;
    int tx = threadIdx.x & 31, ty = threadIdx.x >> 5;

    const float* xb = x + (long)z * 512 * 4096;
    #pragma unroll
    for (int i = 0; i < 4; i++)
        tile[ty + i * 8][tx] = xb[(long)(c0 + ty + i * 8) * 4096 + n0 + tx];
    __syncthreads();

    __hip_bfloat16* xTb = xT + (long)z * 4096 * 512;
    #pragma unroll
    for (int i = 0; i < 4; i++) {
        int nl = ty + i * 8;
        xTb[(long)(n0 + nl) * 512 + c0 + tx] = __float2bfloat16(tile[tx][nl]);
    }
}

// 512x512 transpose+cast: wqT[c][o] = wq[o][c]
__global__ __launch_bounds__(256) void transpose_cast_sq(
    const float* __restrict__ in, __hip_bfloat16* __restrict__ out)
{
    __shared__ float tile[32][33];
    int r0 = blockIdx.y * 32, c0 = blockIdx.x * 32;
    int tx = threadIdx.x & 31, ty = threadIdx.x >> 5;
    #pragma unroll
    for (int i = 0; i < 4; i++)
        tile[ty + i * 8][tx] = in[(long)(r0 + ty + i * 8) * 512 + c0 + tx];
    __syncthreads();
    #pragma unroll
    for (int i = 0; i < 4; i++)
        out[(long)(c0 + ty + i * 8) * 512 + r0 + tx] = __float2bfloat16(tile[tx][ty + i * 8]);
}

__global__ __launch_bounds__(256) void cast_bf(
    const float* __restrict__ in, __hip_bfloat16* __restrict__ out, int n)
{
    for (int i = blockIdx.x * 256 + threadIdx.x; i < n; i += gridDim.x * 256)
        out[i] = __float2bfloat16(in[i]);
}

// ---------------------------------------------------------------------------
// Per-row stats for softmax: stats[row] = (max, 1/sum_exp). 8192 K-rows.
// ---------------------------------------------------------------------------
__global__ __launch_bounds__(256) void row_stats(
    const __hip_bfloat16* __restrict__ kv, float2* __restrict__ stats)
{
    int b = blockIdx.x >> 9;
    int r = blockIdx.x & 511;
    const unsigned short* row = (const unsigned short*)(kv + ((long)b * 1024 + r) * 4096);

    int t = threadIdx.x, lane = t & 63, wv = t >> 6;
    __shared__ float red[8];

    float vals[16];
    float m = -INFINITY;
    #pragma unroll
    for (int i = 0; i < 2; i++) {
        uint4 raw = *(const uint4*)&row[8 * t + 2048 * i];
        unsigned v[4] = {raw.x, raw.y, raw.z, raw.w};
        #pragma unroll
        for (int j = 0; j < 4; j++) {
            float lo = __uint_as_float(v[j] << 16);
            float hi = __uint_as_float(v[j] & 0xffff0000u);
            vals[i * 8 + j * 2]     = lo;
            vals[i * 8 + j * 2 + 1] = hi;
            m = fmaxf(m, fmaxf(lo, hi));
        }
    }
    #pragma unroll
    for (int off = 32; off > 0; off >>= 1) m = fmaxf(m, __shfl_down(m, off));
    if (lane == 0) red[wv] = m;
    __syncthreads();
    if (t == 0) red[0] = fmaxf(fmaxf(red[0], red[1]), fmaxf(red[2], red[3]));
    __syncthreads();
    m = red[0];

    float s = 0.0f;
    #pragma unroll
    for (int i = 0; i < 16; i++) s += __expf(vals[i] - m);
    #pragma unroll
    for (int off = 32; off > 0; off >>= 1) s += __shfl_down(s, off);
    if (lane == 0) red[4 + wv] = s;
    __syncthreads();
    if (t == 0) {
        float stot = red[4] + red[5] + red[6] + red[7];
        stats[blockIdx.x] = make_float2(m, 1.0f / stot);
    }
}

// ---------------------------------------------------------------------------
// ctx partials: per (ks, bh) block, ctx_part = exp(K-m)*inv_s @ V^T over a
// 512-wide n-chunk. 64x64 output, BK=32, MFMA. P staged via VALU exp; V async.
// ---------------------------------------------------------------------------
__global__ __launch_bounds__(256) void ctx_mfma(
    const __hip_bfloat16* __restrict__ kv, const float2* __restrict__ stats,
    float* __restrict__ part)
{
    int ks = blockIdx.x, bh = blockIdx.y;
    int b = bh >> 3, h = bh & 7;
    const __hip_bfloat16* Krow = kv + ((long)b * 1024 + h * 64) * 4096 + ks * 512;
    const __hip_bfloat16* Vrow = kv + ((long)b * 1024 + 512 + h * 64) * 4096 + ks * 512;

    __shared__ __bf16 Ps[64 * 32];
    __shared__ __bf16 Vs[64 * 32];

    int t = threadIdx.x, lane = t & 63, wv = t >> 6;
    int lr = lane & 15, kg = lane >> 4;

    int prow = t >> 2, pc = (t & 3) * 8;
    float2 s2 = stats[b * 512 + h * 64 + prow];
    float pm = s2.x, pinv = s2.y;

    f32x4 acc[4] = {};

    for (int k0 = 0; k0 < 512; k0 += 32) {
        {
            int vrow = wv * 16 + (lane >> 2);
            int vc   = (lane & 3) * 8;
            async_ld16(Vrow + (long)vrow * 4096 + k0 + vc, &Vs[wv * 16 * 32 + lane * 8]);
        }
        {
            uint4 raw = *(const uint4*)(Krow + (long)prow * 4096 + k0 + pc);
            unsigned v[4] = {raw.x, raw.y, raw.z, raw.w};
            __hip_bfloat16 pb[8];
            #pragma unroll
            for (int j = 0; j < 4; j++) {
                float lo = __uint_as_float(v[j] << 16);
                float hi = __uint_as_float(v[j] & 0xffff0000u);
                pb[j * 2]     = __float2bfloat16(__expf(lo - pm) * pinv);
                pb[j * 2 + 1] = __float2bfloat16(__expf(hi - pm) * pinv);
            }
            *(bf16x8*)&Ps[prow * 32 + pc] = *(const bf16x8*)pb;
        }
        __syncthreads();

        bf16x8 af = *(const bf16x8*)&Ps[(wv * 16 + lr) * 32 + kg * 8];
        #pragma unroll
        for (int j = 0; j < 4; j++) {
            bf16x8 bfr = *(const bf16x8*)&Vs[(j * 16 + lr) * 32 + kg * 8];
            acc[j] = __builtin_amdgcn_mfma_f32_16x16x32_bf16(af, bfr, acc[j], 0, 0, 0);
        }
        __syncthreads();
    }

    float* P = part + ((long)bh * 8 + ks) * 4096;
    #pragma unroll
    for (int j = 0; j < 4; j++)
        #pragma unroll
        for (int r = 0; r < 4; r++)
            P[(wv * 16 + kg * 4 + r) * 64 + j * 16 + lr] = acc[j][r];
}

__global__ __launch_bounds__(256) void reduce_ctx(
    const float* __restrict__ part, float* __restrict__ ctx)
{
    int bh = blockIdx.x;
    for (int i = threadIdx.x; i < 4096; i += 256) {
        float s = 0.0f;
        #pragma unroll
        for (int ks = 0; ks < 8; ks++)
            s += part[((long)bh * 8 + ks) * 4096 + i];
        ctx[(long)bh * 4096 + i] = s;
    }
}

// ---------------------------------------------------------------------------
// fp32 64x64 GEMM for W2 build (MODE2 addressing), bf16 output.
// ---------------------------------------------------------------------------
__global__ __launch_bounds__(256) void gemm64_w2(
    const float* __restrict__ A, const float* __restrict__ Bm,
    __hip_bfloat16* __restrict__ Cb)
{
    const int t  = threadIdx.x;
    const int tx = t & 15;
    const int ty = t >> 4;
    const int z  = blockIdx.z;

    int row0 = blockIdx.y * 64;

    long aBase = (long)(z & 7) * 64;
    long bBase = (long)z * 4096;
    long cBase = (long)(z >> 3) * 262144 + (long)(z & 7) * 64;

    __shared__ __align__(16) float As[16][68];
    __shared__ __align__(16) float Bs[16][68];

    float acc[4][4] = {};

    for (int k0 = 0; k0 < 64; k0 += 16) {
        {
            int k = t & 15, r = t >> 4;
            #pragma unroll
            for (int i = 0; i < 4; i++)
                As[k][r + i * 16] = A[aBase + (long)(row0 + r + i * 16) * 512 + k0 + k];
        }
        {
            int k = t & 15, c = t >> 4;
            #pragma unroll
            for (int i = 0; i < 4; i++)
                Bs[k][c + i * 16] = Bm[bBase + (long)(c + i * 16) * 64 + k0 + k];
        }
        __syncthreads();

        #pragma unroll
        for (int kk = 0; kk < 16; kk++) {
            float4 a4 = *(const float4*)&As[kk][ty * 4];
            float4 b4 = *(const float4*)&Bs[kk][tx * 4];
            float av[4] = {a4.x, a4.y, a4.z, a4.w};
            float bv[4] = {b4.x, b4.y, b4.z, b4.w};
            #pragma unroll
            for (int i = 0; i < 4; i++)
                #pragma unroll
                for (int j = 0; j < 4; j++)
                    acc[i][j] = fmaf(av[i], bv[j], acc[i][j]);
        }
        __syncthreads();
    }

    #pragma unroll
    for (int i = 0; i < 4; i++) {
        int r = row0 + ty * 4 + i;
        __hip_bfloat16 o4[4];
        #pragma unroll
        for (int j = 0; j < 4; j++) o4[j] = __float2bfloat16(acc[i][j]);
        *(short4*)&Cb[cBase + (long)r * 512 + tx * 4] = *(const short4*)o4;
    }
}

extern "C" void kernel_launch(void* const* d_in, const int* in_sizes, int n_in,
                              void* d_out, int out_size, void* d_ws, size_t ws_size,
                              hipStream_t stream)
{
    const float* x     = (const float*)d_in[0];   // (16, 512, 4096)
    const float* w_qkv = (const float*)d_in[1];   // (1536, 512)
    const float* w_out = (const float*)d_in[2];   // (512, 512)
    const float* b_out = (const float*)d_in[3];   // (512,)
    float* out = (float*)d_out;                   // (16, 512, 4096)

    char* ws = (char*)d_ws;
    __hip_bfloat16* kv_bf  = (__hip_bfloat16*)(ws);                 // 134,217,728
    __hip_bfloat16* xT     = (__hip_bfloat16*)(ws + 134217728L);    //  67,108,864
    float*          ctxp   = (float*)(ws + 201326592L);             //  16,777,216
    float*          ctx    = (float*)(ws + 218103808L);             //   2,097,152
    __hip_bfloat16* w2bf   = (__hip_bfloat16*)(ws + 220200960L);    //   8,388,608
    __hip_bfloat16* w3bf   = (__hip_bfloat16*)(ws + 228589568L);    //   8,388,608
    __hip_bfloat16* wkvbf  = (__hip_bfloat16*)(ws + 236978176L);    //   1,048,576
    __hip_bfloat16* wqT    = (__hip_bfloat16*)(ws + 238026752L);    //     524,288
    float2*         stats  = (float2*)(ws + 238551040L);            //      65,536

    // 0. transposes + casts
    transpose_cast<<<dim3(128, 16, 16), 256, 0, stream>>>(x, xT);
    cast_bf<<<dim3(512), 256, 0, stream>>>(w_qkv + 512 * 512, wkvbf, 1024 * 512);
    transpose_cast_sq<<<dim3(16, 16), 256, 0, stream>>>(w_qkv, wqT);

    // 1. kv[b] = Wkv @ x[b]   (M=1024, N=4096, K=512) -> bf16   [256^2 pipe]
    gemm256<true, false><<<dim3(16, 4, 16), 512, 0, stream>>>(
        (const __bf16*)wkvbf, (const __bf16*)xT, kv_bf, nullptr,
        512, 4096, 0L, (long)4096 * 512, (long)1024 * 4096);

    // 2. per-row softmax stats on K rows
    row_stats<<<dim3(8192), 256, 0, stream>>>(kv_bf, stats);

    // 3. ctx partials (exp fused) + reduce
    ctx_mfma<<<dim3(8, 128), 256, 0, stream>>>(kv_bf, stats, ctxp);
    reduce_ctx<<<dim3(128), 256, 0, stream>>>(ctxp, ctx);

    // 4. W2 build -> bf16
    gemm64_w2<<<dim3(1, 8, 128), 256, 0, stream>>>(w_out, ctx, w2bf);

    // 5. W3[b] = W2[b] @ Wq  (M=512, N=512, K=512) -> bf16   [old 128^2]
    gemm_mfma<true, false><<<dim3(4, 4, 16), 256, 0, stream>>>(
        (const __bf16*)w2bf, (const __bf16*)wqT, w3bf, nullptr,
        512, 512, 262144L, 0L, 262144L);

    // 6. out[b] = W3[b] @ x[b] + b_out  (M=512, N=4096, K=512)  [256^2 pipe]
    gemm256<false, true><<<dim3(16, 2, 16), 512, 0, stream>>>(
        (const __bf16*)w3bf, (const __bf16*)xT, out, b_out,
        512, 4096, (long)512 * 512, (long)4096 * 512, (long)512 * 4096);
}

// Round 5
// 519.885 us; speedup vs baseline: 1.0060x; 1.0060x over previous
//
#include <hip/hip_runtime.h>
#include <hip/hip_bf16.h>
#include <math.h>

// LinearAttention: b=16, c=512, n=4096, heads=8, dim_head=64, hidden=512.
// R8 = R7 minus ALL sched_barrier(0) in gemm256 (m141 lesson: order-pinning
// defeats compiler scheduling; 0.58x regression signature matched our 0.57x).
// s_barrier alone fences memory-op motion; slot-overwrite safety preserved.
//  0. xT[b] (4096x512 bf16) = transpose+cast x; wkv bf16; WqT bf16
//  1. kv[b] (1024x4096 bf16) = Wkv @ x  [gemm256 deep-pipe MFMA]  (68.7 GF)
//  2. row_stats: per K-row max & 1/sum_exp (read-only)
//  3. ctx[bh] = softmax(K) @ V^T  [MFMA, exp fused in staging, split-K 8]
//  4. W2[b] = w_out (x) ctx   (fp32 gemm64, writes bf16)
//  5. W3[b] = W2 @ Wq  [old 128^2 MFMA, bf16 out]
//  6. out[b] = W3 @ x + b_out  [gemm256 deep-pipe MFMA, fp32 out] (34.4 GF)

typedef __attribute__((ext_vector_type(8))) __bf16 bf16x8;
typedef __attribute__((ext_vector_type(4))) float f32x4;

__device__ inline void async_ld16(const void* g, void* s) {
    __builtin_amdgcn_global_load_lds(
        (const __attribute__((address_space(1))) void*)g,
        (__attribute__((address_space(3))) void*)s, 16, 0, 0);
}

template<int N> __device__ __forceinline__ void end_wait() {
    if constexpr (N == 8)      asm volatile("s_waitcnt vmcnt(8)" ::: "memory");
    else if constexpr (N == 4) asm volatile("s_waitcnt vmcnt(4)" ::: "memory");
    else if constexpr (N == 0) asm volatile("s_waitcnt vmcnt(0)" ::: "memory");
    // N < 0: no wait
}

// ---------------------------------------------------------------------------
// gemm256: C[m][n] = sum_k A[m][k] * BT[n][k]
// BM=BN=256, BK=32, 512 threads (8 waves: 2M x 4N), 16x16x32 bf16 MFMA.
// LDS: As/Bs 4 slots x [granule kg 0..3][row 0..255] x 16B  (64KB each).
// Pipeline: prologue stages tiles 0..2; iter t computes tile t (2 phases,
// 16 MFMA each), stages tile t+3 (A in phase0, B in phase1), ends with
// vmcnt(8) + barrier (tiles t+2,t+3 = 8 loads stay in flight).
// NO sched_barrier(0): s_barrier already fences memory-op motion; the
// compiler must remain free to overlap ds_read issue with MFMA (m141).
// ---------------------------------------------------------------------------
template<bool STAGE, int ENDVM>
__device__ __forceinline__ void tile_body(
    __bf16* As, __bf16* Bs, int slot, int kt,
    const __bf16* srcA0, const __bf16* srcA1,
    const __bf16* srcB0, const __bf16* srcB1,
    int dstA0, int dstA1, int dstB0, int dstB1,
    int aBaseOff, int bBaseOff, f32x4 (&acc)[8][4])
{
    const int so = slot * 8192;
    bf16x8 bfr[4], af[4];

    // ---- phase 0: quadrant mf 0..3, full K=32 ----
    #pragma unroll
    for (int nf = 0; nf < 4; nf++)
        bfr[nf] = *(const bf16x8*)&Bs[so + bBaseOff + nf * 128];
    #pragma unroll
    for (int mf = 0; mf < 4; mf++)
        af[mf] = *(const bf16x8*)&As[so + aBaseOff + mf * 128];
    if (STAGE) {
        const int ns = (kt & 3) * 8192;
        async_ld16(srcA0 + (long)kt * 32, &As[ns + dstA0]);
        async_ld16(srcA1 + (long)kt * 32, &As[ns + dstA1]);
    }
    __builtin_amdgcn_s_barrier();
    __builtin_amdgcn_s_setprio(1);
    #pragma unroll
    for (int mf = 0; mf < 4; mf++)
        #pragma unroll
        for (int nf = 0; nf < 4; nf++)
            acc[mf][nf] = __builtin_amdgcn_mfma_f32_16x16x32_bf16(af[mf], bfr[nf], acc[mf][nf], 0, 0, 0);
    __builtin_amdgcn_s_setprio(0);
    __builtin_amdgcn_s_barrier();

    // ---- phase 1: quadrant mf 4..7, B frags reused from registers ----
    #pragma unroll
    for (int mf = 0; mf < 4; mf++)
        af[mf] = *(const bf16x8*)&As[so + aBaseOff + (4 + mf) * 128];
    if (STAGE) {
        const int ns = (kt & 3) * 8192;
        async_ld16(srcB0 + (long)kt * 32, &Bs[ns + dstB0]);
        async_ld16(srcB1 + (long)kt * 32, &Bs[ns + dstB1]);
    }
    __builtin_amdgcn_s_barrier();
    __builtin_amdgcn_s_setprio(1);
    #pragma unroll
    for (int mf = 0; mf < 4; mf++)
        #pragma unroll
        for (int nf = 0; nf < 4; nf++)
            acc[4 + mf][nf] = __builtin_amdgcn_mfma_f32_16x16x32_bf16(af[mf], bfr[nf], acc[4 + mf][nf], 0, 0, 0);
    __builtin_amdgcn_s_setprio(0);
    end_wait<ENDVM>();
    __builtin_amdgcn_s_barrier();
}

template<bool OUTBF, bool BIAS>
__global__ __launch_bounds__(512, 2) void gemm256(
    const __bf16* __restrict__ A, const __bf16* __restrict__ BT,
    void* __restrict__ Cv, const float* __restrict__ bias,
    int K, int N, long aBS, long bBS, long cBS)
{
    __shared__ __align__(16) __bf16 As[4 * 8192];   // 64 KiB
    __shared__ __align__(16) __bf16 Bs[4 * 8192];   // 64 KiB

    const int tid  = threadIdx.x;
    const int lane = tid & 63, wv = tid >> 6;
    const int lr = lane & 15, kg = lane >> 4;
    const int wm = wv >> 2, wn = wv & 3;            // 2 M-waves x 4 N-waves

    // --- XCD-chunked bijective grid swizzle ---
    const int gx = gridDim.x, gy = gridDim.y;
    const unsigned nwg = gx * gy * gridDim.z;
    const unsigned orig = (blockIdx.z * gy + blockIdx.y) * gx + blockIdx.x;
    const unsigned q = nwg >> 3;
    const unsigned w = (orig & 7) * q + (orig >> 3);
    const unsigned perz = gx * gy;
    const int z  = w / perz;
    const unsigned rem = w - z * perz;
    const int by = rem / gx, bx = rem - (rem / gx) * gx;
    const int row0 = by * 256, col0 = bx * 256;

    A  += (long)z * aBS;
    BT += (long)z * bBS;

    // --- staging assignment: thread covers (granule g, row r) slots ---
    const int rowS = tid & 255;
    const int gA0 = (tid >> 8);                     // load 0: g = 0 or 1
    const int gA1 = gA0 + 2;                        // load 1: g = 2 or 3
    const __bf16* srcA0 = A + (long)(row0 + rowS) * K + gA0 * 8;
    const __bf16* srcA1 = A + (long)(row0 + rowS) * K + gA1 * 8;
    const __bf16* srcB0 = BT + (long)(col0 + rowS) * K + gA0 * 8;
    const __bf16* srcB1 = BT + (long)(col0 + rowS) * K + gA1 * 8;
    const int dstA0 = gA0 * 2048 + rowS * 8;
    const int dstA1 = gA1 * 2048 + rowS * 8;
    const int dstB0 = dstA0;                        // Bs has identical layout
    const int dstB1 = dstA1;

    // --- fragment read offsets (granule-major: [kg][row] of 16B) ---
    const int aBaseOff = kg * 2048 + (wm * 128 + lr) * 8;
    const int bBaseOff = kg * 2048 + (wn * 64 + lr) * 8;

    f32x4 acc[8][4] = {};

    const int nt = K >> 5;                          // 32-wide K tiles (=16)

    // --- prologue: stage tiles 0,1,2 into slots 0,1,2 ---
    #pragma unroll
    for (int p = 0; p < 3; p++) {
        const int ns = p * 8192;
        async_ld16(srcA0 + p * 32, &As[ns + dstA0]);
        async_ld16(srcA1 + p * 32, &As[ns + dstA1]);
        async_ld16(srcB0 + p * 32, &Bs[ns + dstB0]);
        async_ld16(srcB1 + p * 32, &Bs[ns + dstB1]);
    }
    asm volatile("s_waitcnt vmcnt(8)" ::: "memory"); // tile 0 resident
    __builtin_amdgcn_s_barrier();

    int t = 0;
    for (; t < nt - 3; ++t)
        tile_body<true, 8>(As, Bs, t & 3, t + 3, srcA0, srcA1, srcB0, srcB1,
                           dstA0, dstA1, dstB0, dstB1, aBaseOff, bBaseOff, acc);
    tile_body<false, 4>(As, Bs, t & 3, 0, srcA0, srcA1, srcB0, srcB1,
                        dstA0, dstA1, dstB0, dstB1, aBaseOff, bBaseOff, acc); ++t;
    tile_body<false, 0>(As, Bs, t & 3, 0, srcA0, srcA1, srcB0, srcB1,
                        dstA0, dstA1, dstB0, dstB1, aBaseOff, bBaseOff, acc); ++t;
    tile_body<false, -1>(As, Bs, t & 3, 0, srcA0, srcA1, srcB0, srcB1,
                         dstA0, dstA1, dstB0, dstB1, aBaseOff, bBaseOff, acc);

    // --- epilogue ---
    const int kg4 = kg * 4;
    #pragma unroll
    for (int mf = 0; mf < 8; mf++) {
        #pragma unroll
        for (int nf = 0; nf < 4; nf++) {
            #pragma unroll
            for (int rr = 0; rr < 4; rr++) {
                int row = row0 + wm * 128 + mf * 16 + kg4 + rr;
                int col = col0 + wn * 64 + nf * 16 + lr;
                float v = acc[mf][nf][rr];
                if (OUTBF) {
                    ((__hip_bfloat16*)Cv)[(long)z * cBS + (long)row * N + col] = __float2bfloat16(v);
                } else {
                    if (BIAS) v += bias[row];
                    ((float*)Cv)[(long)z * cBS + (long)row * N + col] = v;
                }
            }
        }
    }
}

// ---------------------------------------------------------------------------
// Old 128x128 MFMA GEMM (kept for W3: M=N=512, grid too small for 256^2)
// ---------------------------------------------------------------------------
template<bool OUTBF, bool BIAS>
__global__ __launch_bounds__(256) void gemm_mfma(
    const __bf16* __restrict__ A, const __bf16* __restrict__ BT,
    void* __restrict__ Cv, const float* __restrict__ bias,
    int K, int N, long aBS, long bBS, long cBS)
{
    __shared__ __bf16 As[128 * 64];
    __shared__ __bf16 Bs[128 * 64];

    const int t = threadIdx.x;
    const int lane = t & 63, wv = t >> 6;
    const int z = blockIdx.z;

    const int nx = gridDim.x, ny = gridDim.y;
    const int orig = blockIdx.y * nx + blockIdx.x;
    const int cpx = (nx * ny) >> 3;
    const int w = (orig & 7) * cpx + (orig >> 3);
    const int bx = w / ny, by = w % ny;
    const int row0 = by * 128, col0 = bx * 128;

    A  += (long)z * aBS;
    BT += (long)z * bBS;

    const int wm = (wv >> 1) * 64, wn = (wv & 1) * 64;
    const int lr = lane & 15, kg = lane >> 4;

    f32x4 acc[4][4] = {};

    const int srow = t >> 3;
    const int gsrc = (t & 7) ^ ((t >> 3) & 7);
    const int swzR = lr & 7;

    for (int k0 = 0; k0 < K; k0 += 64) {
        #pragma unroll
        for (int rnd = 0; rnd < 4; rnd++) {
            int r = rnd * 32 + srow;
            async_ld16(A  + (long)(row0 + r) * K + k0 + gsrc * 8, &As[rnd * 2048 + t * 8]);
            async_ld16(BT + (long)(col0 + r) * K + k0 + gsrc * 8, &Bs[rnd * 2048 + t * 8]);
        }
        __syncthreads();

        #pragma unroll
        for (int kk = 0; kk < 2; kk++) {
            bf16x8 af[4], bfr[4];
            int ga = ((kk << 2) | kg) ^ swzR;
            #pragma unroll
            for (int i = 0; i < 4; i++) {
                af[i]  = *(const bf16x8*)&As[(wm + i * 16 + lr) * 64 + ga * 8];
                bfr[i] = *(const bf16x8*)&Bs[(wn + i * 16 + lr) * 64 + ga * 8];
            }
            #pragma unroll
            for (int i = 0; i < 4; i++)
                #pragma unroll
                for (int j = 0; j < 4; j++)
                    acc[i][j] = __builtin_amdgcn_mfma_f32_16x16x32_bf16(af[i], bfr[j], acc[i][j], 0, 0, 0);
        }
        __syncthreads();
    }

    #pragma unroll
    for (int i = 0; i < 4; i++) {
        #pragma unroll
        for (int j = 0; j < 4; j++) {
            #pragma unroll
            for (int r = 0; r < 4; r++) {
                int row = row0 + wm + i * 16 + kg * 4 + r;
                int col = col0 + wn + j * 16 + lr;
                float v = acc[i][j][r];
                if (OUTBF) {
                    ((__hip_bfloat16*)Cv)[(long)z * cBS + (long)row * N + col] = __float2bfloat16(v);
                } else {
                    if (BIAS) v += bias[row];
                    ((float*)Cv)[(long)z * cBS + (long)row * N + col] = v;
                }
            }
        }
    }
}

// ---------------------------------------------------------------------------
// Transpose+cast: x (16,512,4096) f32 -> xT (16,4096,512) bf16
// ---------------------------------------------------------------------------
__global__ __launch_bounds__(256) void transpose_cast(
    const float* __restrict__ x, __hip_bfloat16* __restrict__ xT)
{
    __shared__ float tile[32][33];
    int z = blockIdx.z;
    int n0 = blockIdx.x * 32, c0 = blockIdx.y * 32;
    int tx = threadIdx.x & 31, ty = threadIdx.x >> 5;

    const float* xb = x + (long)z * 512 * 4096;
    #pragma unroll
    for (int i = 0; i < 4; i++)
        tile[ty + i * 8][tx] = xb[(long)(c0 + ty + i * 8) * 4096 + n0 + tx];
    __syncthreads();

    __hip_bfloat16* xTb = xT + (long)z * 4096 * 512;
    #pragma unroll
    for (int i = 0; i < 4; i++) {
        int nl = ty + i * 8;
        xTb[(long)(n0 + nl) * 512 + c0 + tx] = __float2bfloat16(tile[tx][nl]);
    }
}

// 512x512 transpose+cast: wqT[c][o] = wq[o][c]
__global__ __launch_bounds__(256) void transpose_cast_sq(
    const float* __restrict__ in, __hip_bfloat16* __restrict__ out)
{
    __shared__ float tile[32][33];
    int r0 = blockIdx.y * 32, c0 = blockIdx.x * 32;
    int tx = threadIdx.x & 31, ty = threadIdx.x >> 5;
    #pragma unroll
    for (int i = 0; i < 4; i++)
        tile[ty + i * 8][tx] = in[(long)(r0 + ty + i * 8) * 512 + c0 + tx];
    __syncthreads();
    #pragma unroll
    for (int i = 0; i < 4; i++)
        out[(long)(c0 + ty + i * 8) * 512 + r0 + tx] = __float2bfloat16(tile[tx][ty + i * 8]);
}

__global__ __launch_bounds__(256) void cast_bf(
    const float* __restrict__ in, __hip_bfloat16* __restrict__ out, int n)
{
    for (int i = blockIdx.x * 256 + threadIdx.x; i < n; i += gridDim.x * 256)
        out[i] = __float2bfloat16(in[i]);
}

// ---------------------------------------------------------------------------
// Per-row stats for softmax: stats[row] = (max, 1/sum_exp). 8192 K-rows.
// ---------------------------------------------------------------------------
__global__ __launch_bounds__(256) void row_stats(
    const __hip_bfloat16* __restrict__ kv, float2* __restrict__ stats)
{
    int b = blockIdx.x >> 9;
    int r = blockIdx.x & 511;
    const unsigned short* row = (const unsigned short*)(kv + ((long)b * 1024 + r) * 4096);

    int t = threadIdx.x, lane = t & 63, wv = t >> 6;
    __shared__ float red[8];

    float vals[16];
    float m = -INFINITY;
    #pragma unroll
    for (int i = 0; i < 2; i++) {
        uint4 raw = *(const uint4*)&row[8 * t + 2048 * i];
        unsigned v[4] = {raw.x, raw.y, raw.z, raw.w};
        #pragma unroll
        for (int j = 0; j < 4; j++) {
            float lo = __uint_as_float(v[j] << 16);
            float hi = __uint_as_float(v[j] & 0xffff0000u);
            vals[i * 8 + j * 2]     = lo;
            vals[i * 8 + j * 2 + 1] = hi;
            m = fmaxf(m, fmaxf(lo, hi));
        }
    }
    #pragma unroll
    for (int off = 32; off > 0; off >>= 1) m = fmaxf(m, __shfl_down(m, off));
    if (lane == 0) red[wv] = m;
    __syncthreads();
    if (t == 0) red[0] = fmaxf(fmaxf(red[0], red[1]), fmaxf(red[2], red[3]));
    __syncthreads();
    m = red[0];

    float s = 0.0f;
    #pragma unroll
    for (int i = 0; i < 16; i++) s += __expf(vals[i] - m);
    #pragma unroll
    for (int off = 32; off > 0; off >>= 1) s += __shfl_down(s, off);
    if (lane == 0) red[4 + wv] = s;
    __syncthreads();
    if (t == 0) {
        float stot = red[4] + red[5] + red[6] + red[7];
        stats[blockIdx.x] = make_float2(m, 1.0f / stot);
    }
}

// ---------------------------------------------------------------------------
// ctx partials: per (ks, bh) block, ctx_part = exp(K-m)*inv_s @ V^T over a
// 512-wide n-chunk. 64x64 output, BK=32, MFMA. P staged via VALU exp; V async.
// ---------------------------------------------------------------------------
__global__ __launch_bounds__(256) void ctx_mfma(
    const __hip_bfloat16* __restrict__ kv, const float2* __restrict__ stats,
    float* __restrict__ part)
{
    int ks = blockIdx.x, bh = blockIdx.y;
    int b = bh >> 3, h = bh & 7;
    const __hip_bfloat16* Krow = kv + ((long)b * 1024 + h * 64) * 4096 + ks * 512;
    const __hip_bfloat16* Vrow = kv + ((long)b * 1024 + 512 + h * 64) * 4096 + ks * 512;

    __shared__ __bf16 Ps[64 * 32];
    __shared__ __bf16 Vs[64 * 32];

    int t = threadIdx.x, lane = t & 63, wv = t >> 6;
    int lr = lane & 15, kg = lane >> 4;

    int prow = t >> 2, pc = (t & 3) * 8;
    float2 s2 = stats[b * 512 + h * 64 + prow];
    float pm = s2.x, pinv = s2.y;

    f32x4 acc[4] = {};

    for (int k0 = 0; k0 < 512; k0 += 32) {
        {
            int vrow = wv * 16 + (lane >> 2);
            int vc   = (lane & 3) * 8;
            async_ld16(Vrow + (long)vrow * 4096 + k0 + vc, &Vs[wv * 16 * 32 + lane * 8]);
        }
        {
            uint4 raw = *(const uint4*)(Krow + (long)prow * 4096 + k0 + pc);
            unsigned v[4] = {raw.x, raw.y, raw.z, raw.w};
            __hip_bfloat16 pb[8];
            #pragma unroll
            for (int j = 0; j < 4; j++) {
                float lo = __uint_as_float(v[j] << 16);
                float hi = __uint_as_float(v[j] & 0xffff0000u);
                pb[j * 2]     = __float2bfloat16(__expf(lo - pm) * pinv);
                pb[j * 2 + 1] = __float2bfloat16(__expf(hi - pm) * pinv);
            }
            *(bf16x8*)&Ps[prow * 32 + pc] = *(const bf16x8*)pb;
        }
        __syncthreads();

        bf16x8 af = *(const bf16x8*)&Ps[(wv * 16 + lr) * 32 + kg * 8];
        #pragma unroll
        for (int j = 0; j < 4; j++) {
            bf16x8 bfr = *(const bf16x8*)&Vs[(j * 16 + lr) * 32 + kg * 8];
            acc[j] = __builtin_amdgcn_mfma_f32_16x16x32_bf16(af, bfr, acc[j], 0, 0, 0);
        }
        __syncthreads();
    }

    float* P = part + ((long)bh * 8 + ks) * 4096;
    #pragma unroll
    for (int j = 0; j < 4; j++)
        #pragma unroll
        for (int r = 0; r < 4; r++)
            P[(wv * 16 + kg * 4 + r) * 64 + j * 16 + lr] = acc[j][r];
}

__global__ __launch_bounds__(256) void reduce_ctx(
    const float* __restrict__ part, float* __restrict__ ctx)
{
    int bh = blockIdx.x;
    for (int i = threadIdx.x; i < 4096; i += 256) {
        float s = 0.0f;
        #pragma unroll
        for (int ks = 0; ks < 8; ks++)
            s += part[((long)bh * 8 + ks) * 4096 + i];
        ctx[(long)bh * 4096 + i] = s;
    }
}

// ---------------------------------------------------------------------------
// fp32 64x64 GEMM for W2 build (MODE2 addressing), bf16 output.
// ---------------------------------------------------------------------------
__global__ __launch_bounds__(256) void gemm64_w2(
    const float* __restrict__ A, const float* __restrict__ Bm,
    __hip_bfloat16* __restrict__ Cb)
{
    const int t  = threadIdx.x;
    const int tx = t & 15;
    const int ty = t >> 4;
    const int z  = blockIdx.z;

    int row0 = blockIdx.y * 64;

    long aBase = (long)(z & 7) * 64;
    long bBase = (long)z * 4096;
    long cBase = (long)(z >> 3) * 262144 + (long)(z & 7) * 64;

    __shared__ __align__(16) float As[16][68];
    __shared__ __align__(16) float Bs[16][68];

    float acc[4][4] = {};

    for (int k0 = 0; k0 < 64; k0 += 16) {
        {
            int k = t & 15, r = t >> 4;
            #pragma unroll
            for (int i = 0; i < 4; i++)
                As[k][r + i * 16] = A[aBase + (long)(row0 + r + i * 16) * 512 + k0 + k];
        }
        {
            int k = t & 15, c = t >> 4;
            #pragma unroll
            for (int i = 0; i < 4; i++)
                Bs[k][c + i * 16] = Bm[bBase + (long)(c + i * 16) * 64 + k0 + k];
        }
        __syncthreads();

        #pragma unroll
        for (int kk = 0; kk < 16; kk++) {
            float4 a4 = *(const float4*)&As[kk][ty * 4];
            float4 b4 = *(const float4*)&Bs[kk][tx * 4];
            float av[4] = {a4.x, a4.y, a4.z, a4.w};
            float bv[4] = {b4.x, b4.y, b4.z, b4.w};
            #pragma unroll
            for (int i = 0; i < 4; i++)
                #pragma unroll
                for (int j = 0; j < 4; j++)
                    acc[i][j] = fmaf(av[i], bv[j], acc[i][j]);
        }
        __syncthreads();
    }

    #pragma unroll
    for (int i = 0; i < 4; i++) {
        int r = row0 + ty * 4 + i;
        __hip_bfloat16 o4[4];
        #pragma unroll
        for (int j = 0; j < 4; j++) o4[j] = __float2bfloat16(acc[i][j]);
        *(short4*)&Cb[cBase + (long)r * 512 + tx * 4] = *(const short4*)o4;
    }
}

extern "C" void kernel_launch(void* const* d_in, const int* in_sizes, int n_in,
                              void* d_out, int out_size, void* d_ws, size_t ws_size,
                              hipStream_t stream)
{
    const float* x     = (const float*)d_in[0];   // (16, 512, 4096)
    const float* w_qkv = (const float*)d_in[1];   // (1536, 512)
    const float* w_out = (const float*)d_in[2];   // (512, 512)
    const float* b_out = (const float*)d_in[3];   // (512,)
    float* out = (float*)d_out;                   // (16, 512, 4096)

    char* ws = (char*)d_ws;
    __hip_bfloat16* kv_bf  = (__hip_bfloat16*)(ws);                 // 134,217,728
    __hip_bfloat16* xT     = (__hip_bfloat16*)(ws + 134217728L);    //  67,108,864
    float*          ctxp   = (float*)(ws + 201326592L);             //  16,777,216
    float*          ctx    = (float*)(ws + 218103808L);             //   2,097,152
    __hip_bfloat16* w2bf   = (__hip_bfloat16*)(ws + 220200960L);    //   8,388,608
    __hip_bfloat16* w3bf   = (__hip_bfloat16*)(ws + 228589568L);    //   8,388,608
    __hip_bfloat16* wkvbf  = (__hip_bfloat16*)(ws + 236978176L);    //   1,048,576
    __hip_bfloat16* wqT    = (__hip_bfloat16*)(ws + 238026752L);    //     524,288
    float2*         stats  = (float2*)(ws + 238551040L);            //      65,536

    // 0. transposes + casts
    transpose_cast<<<dim3(128, 16, 16), 256, 0, stream>>>(x, xT);
    cast_bf<<<dim3(512), 256, 0, stream>>>(w_qkv + 512 * 512, wkvbf, 1024 * 512);
    transpose_cast_sq<<<dim3(16, 16), 256, 0, stream>>>(w_qkv, wqT);

    // 1. kv[b] = Wkv @ x[b]   (M=1024, N=4096, K=512) -> bf16   [256^2 pipe]
    gemm256<true, false><<<dim3(16, 4, 16), 512, 0, stream>>>(
        (const __bf16*)wkvbf, (const __bf16*)xT, kv_bf, nullptr,
        512, 4096, 0L, (long)4096 * 512, (long)1024 * 4096);

    // 2. per-row softmax stats on K rows
    row_stats<<<dim3(8192), 256, 0, stream>>>(kv_bf, stats);

    // 3. ctx partials (exp fused) + reduce
    ctx_mfma<<<dim3(8, 128), 256, 0, stream>>>(kv_bf, stats, ctxp);
    reduce_ctx<<<dim3(128), 256, 0, stream>>>(ctxp, ctx);

    // 4. W2 build -> bf16
    gemm64_w2<<<dim3(1, 8, 128), 256, 0, stream>>>(w_out, ctx, w2bf);

    // 5. W3[b] = W2[b] @ Wq  (M=512, N=512, K=512) -> bf16   [old 128^2]
    gemm_mfma<true, false><<<dim3(4, 4, 16), 256, 0, stream>>>(
        (const __bf16*)w2bf, (const __bf16*)wqT, w3bf, nullptr,
        512, 512, 262144L, 0L, 262144L);

    // 6. out[b] = W3[b] @ x[b] + b_out  (M=512, N=4096, K=512)  [256^2 pipe]
    gemm256<false, true><<<dim3(16, 2, 16), 512, 0, stream>>>(
        (const __bf16*)w3bf, (const __bf16*)xT, out, b_out,
        512, 4096, (long)512 * 512, (long)4096 * 512, (long)512 * 4096);
}